// Round 15
// baseline (139.224 us; speedup 1.0000x reference)
//
#include <hip/hip_runtime.h>

// loss_separation: sum_{b, i != j} exp(-0.5 * ||kp[b,i] - kp[b,j]||)
// B=32, N=2048 fp32 -> scalar fp32.
// Symmetry: 2*sum_{i<j}; upper-tri 128x128 tile pairs.
// R7: Schraudolph exp2 + SoA LDS + v_pk math (best: 67.7us).
// R14: fuse the stage-2 reduce via last-block-done: partials -> d_ws,
// __threadfence + counter atomicAdd; last block reduces 4352 partials and
// writes d_out. Saves one kernel launch + stage2 + d_out memset.

#define BATCHES 32
#define NPTS 2048
#define TILE 128
#define TTILES (NPTS / TILE)                 // 16
#define NTPAIRS (TTILES * (TTILES + 1) / 2)  // 136
#define NPARTS (NTPAIRS * BATCHES)           // 4352 = 34 * 128

typedef float vf2 __attribute__((ext_vector_type(2)));
typedef float vf4 __attribute__((ext_vector_type(4)));

// exp2(x) ~= asfloat((int)(x*2^23 + BF)), x <= 0 here.
// K folds -0.5*log2(e) and 2^23. BF = (127 - 0.0564)*2^23 + 0.5.
#define K_EXP  (-6051102.0f)        // -0.72134752 * 8388608
#define BF_EXP (1064880100.0f)      // (127 - 0.0564) * 2^23 + 0.5

__global__ __launch_bounds__(TILE)
void loss_sep_kernel(const float2* __restrict__ kp, float* __restrict__ part,
                     int* __restrict__ counter, float* __restrict__ out) {
    const int b = blockIdx.y;

    // Decode upper-triangular tile pair (ti <= tj); uniform SALU loop <=16 iters.
    int t = blockIdx.x;
    int ti = 0;
    while (t >= TTILES - ti) { t -= TTILES - ti; ++ti; }
    const int tj = ti + t;
    const bool diag = (ti == tj);

    const int i0 = ti * TILE;
    const int j0 = tj * TILE;
    const int tid = threadIdx.x;

    __shared__ float kjx[TILE];   // SoA so b128 gives 4 consecutive x's
    __shared__ float kjy[TILE];
    {
        const float2 v = kp[(size_t)b * NPTS + j0 + tid];
        kjx[tid] = v.x;
        kjy[tid] = v.y;
    }
    const float2 ki = kp[(size_t)b * NPTS + i0 + tid];
    __syncthreads();

    const vf4* xs4 = reinterpret_cast<const vf4*>(kjx);
    const vf4* ys4 = reinterpret_cast<const vf4*>(kjy);
    const vf2 kx = {ki.x, ki.x};
    const vf2 ky = {ki.y, ki.y};

    vf2 accA = {0.0f, 0.0f}, accB = {0.0f, 0.0f};
    #pragma unroll 4
    for (int jj = 0; jj < TILE / 4; ++jj) {
        const vf4 xs = xs4[jj];              // ds_read_b128 broadcast
        const vf4 ys = ys4[jj];
        const vf2 dx01 = kx - xs.lo;         // v_pk math
        const vf2 dy01 = ky - ys.lo;
        const vf2 dx23 = kx - xs.hi;
        const vf2 dy23 = ky - ys.hi;
        const vf2 d01 = dx01 * dx01 + dy01 * dy01;
        const vf2 d23 = dx23 * dx23 + dy23 * dy23;
        const float s0 = __builtin_amdgcn_sqrtf(d01.x);  // exact v_sqrt_f32
        const float s1 = __builtin_amdgcn_sqrtf(d01.y);
        const float s2 = __builtin_amdgcn_sqrtf(d23.x);
        const float s3 = __builtin_amdgcn_sqrtf(d23.y);
        const int e0 = (int)fmaf(s0, K_EXP, BF_EXP);     // Schraudolph exp2
        const int e1 = (int)fmaf(s1, K_EXP, BF_EXP);
        const int e2 = (int)fmaf(s2, K_EXP, BF_EXP);
        const int e3 = (int)fmaf(s3, K_EXP, BF_EXP);
        accA += (vf2){__int_as_float(e0), __int_as_float(e1)};
        accB += (vf2){__int_as_float(e2), __int_as_float(e3)};
    }
    const vf2 accp = accA + accB;
    float acc = accp.x + accp.y;
    // Diagonal j==i contributed exactly asfloat((int)BF_EXP) (s==0). Remove it.
    if (diag) acc -= __int_as_float((int)BF_EXP);

    // Wave-64 butterfly reduce
    #pragma unroll
    for (int off = 32; off > 0; off >>= 1)
        acc += __shfl_down(acc, off, 64);

    __shared__ float wsum[TILE / 64];
    __shared__ int s_last;
    if ((tid & 63) == 0) wsum[tid >> 6] = acc;
    __syncthreads();

    if (tid == 0) {
        float tot = wsum[0] + wsum[1];
        if (!diag) tot *= 2.0f;  // unordered pair counted once -> weight 2
        part[b * NTPAIRS + blockIdx.x] = tot;
        __threadfence();                        // release partial (device scope)
        const int old = atomicAdd(counter, 1);  // one counter atomic per block
        s_last = (old == NPARTS - 1) ? 1 : 0;
    }
    __syncthreads();

    if (s_last) {
        // Last block: reduce all partials (visible after fence+atomic).
        __threadfence();
        float r = 0.0f;
        #pragma unroll
        for (int k = 0; k < NPARTS / TILE; ++k)   // 34 coalesced loads
            r += part[k * TILE + tid];
        #pragma unroll
        for (int off = 32; off > 0; off >>= 1)
            r += __shfl_down(r, off, 64);
        if ((tid & 63) == 0) wsum[tid >> 6] = r;
        __syncthreads();
        if (tid == 0) out[0] = wsum[0] + wsum[1];
    }
}

extern "C" void kernel_launch(void* const* d_in, const int* in_sizes, int n_in,
                              void* d_out, int out_size, void* d_ws, size_t ws_size,
                              hipStream_t stream) {
    const float2* kp = (const float2*)d_in[0];
    // d_ws layout: [0..63] counter cacheline, [64..] NPARTS float partials.
    int* counter = (int*)d_ws;
    float* part = (float*)((char*)d_ws + 64);
    float* out = (float*)d_out;

    hipMemsetAsync(counter, 0, sizeof(int), stream);  // graph-capture-safe

    dim3 grid(NTPAIRS, BATCHES);  // 136 x 32 = 4352 two-wave blocks
    loss_sep_kernel<<<grid, TILE, 0, stream>>>(kp, part, counter, out);
}

// Round 19
// 128.934 us; speedup vs baseline: 1.0798x; 1.0798x over previous
//
#include <hip/hip_runtime.h>
#include <hip/hip_cooperative_groups.h>

namespace cg = cooperative_groups;

// loss_separation: sum_{b, i != j} exp(-0.5 * ||kp[b,i] - kp[b,j]||)
// B=32, N=2048 fp32 -> scalar fp32.
// Symmetry: 2*sum_{i<j}; upper-tri 128x128 tile pairs (4352 total).
// R7 loop body (best): Schraudolph exp2 + SoA LDS + v_pk math.
// R16: ONE cooperative kernel. 544 blocks x 8 tiles each, register
// accumulation across tiles, 544 contention-free partials, grid.sync(),
// block 0 reduces. No counter atomics (R14 lesson: 4352 same-address
// atomics = ~65us tail), no stage2 launch, no memsets.

#define BATCHES 32
#define NPTS 2048
#define TILE 128
#define TTILES (NPTS / TILE)                 // 16
#define NTPAIRS (TTILES * (TTILES + 1) / 2)  // 136 per batch
#define NTOT (NTPAIRS * BATCHES)             // 4352 = 544 * 8
#define NBLK 544
#define TPB 128

typedef float vf2 __attribute__((ext_vector_type(2)));
typedef float vf4 __attribute__((ext_vector_type(4)));

// exp2(x) ~= asfloat((int)(x*2^23 + BF)), x <= 0 here.
#define K_EXP  (-6051102.0f)        // -0.5*log2(e) * 2^23
#define BF_EXP (1064880100.0f)      // (127 - 0.0564) * 2^23 + 0.5

__global__ __launch_bounds__(TPB)
void loss_sep_coop(const float2* __restrict__ kp, float* __restrict__ part,
                   float* __restrict__ out) {
    const int tid = threadIdx.x;

    __shared__ float kjx[TILE];   // SoA so b128 gives 4 consecutive x's
    __shared__ float kjy[TILE];
    __shared__ float wsum[2];

    float acc_run = 0.0f;

    #pragma unroll 1
    for (int q = 0; q < NTOT / NBLK; ++q) {       // 8 tiles per block
        const int ft = blockIdx.x * (NTOT / NBLK) + q;
        const int b  = ft / NTPAIRS;
        int t        = ft % NTPAIRS;
        int ti = 0;
        while (t >= TTILES - ti) { t -= TTILES - ti; ++ti; }  // SALU, <=16
        const int tj = ti + t;
        const bool diag = (ti == tj);
        const int i0 = ti * TILE;
        const int j0 = tj * TILE;

        __syncthreads();   // previous tile's LDS reads complete
        {
            const float2 v = kp[(size_t)b * NPTS + j0 + tid];
            kjx[tid] = v.x;
            kjy[tid] = v.y;
        }
        const float2 ki = kp[(size_t)b * NPTS + i0 + tid];
        __syncthreads();

        const vf4* xs4 = reinterpret_cast<const vf4*>(kjx);
        const vf4* ys4 = reinterpret_cast<const vf4*>(kjy);
        const vf2 kx = {ki.x, ki.x};
        const vf2 ky = {ki.y, ki.y};

        vf2 accA = {0.0f, 0.0f}, accB = {0.0f, 0.0f};
        #pragma unroll 4
        for (int jj = 0; jj < TILE / 4; ++jj) {
            const vf4 xs = xs4[jj];              // ds_read_b128 broadcast
            const vf4 ys = ys4[jj];
            const vf2 dx01 = kx - xs.lo;         // v_pk math
            const vf2 dy01 = ky - ys.lo;
            const vf2 dx23 = kx - xs.hi;
            const vf2 dy23 = ky - ys.hi;
            const vf2 d01 = dx01 * dx01 + dy01 * dy01;
            const vf2 d23 = dx23 * dx23 + dy23 * dy23;
            const float s0 = __builtin_amdgcn_sqrtf(d01.x);  // trans pipe
            const float s1 = __builtin_amdgcn_sqrtf(d01.y);
            const float s2 = __builtin_amdgcn_sqrtf(d23.x);
            const float s3 = __builtin_amdgcn_sqrtf(d23.y);
            const int e0 = (int)fmaf(s0, K_EXP, BF_EXP);     // Schraudolph
            const int e1 = (int)fmaf(s1, K_EXP, BF_EXP);
            const int e2 = (int)fmaf(s2, K_EXP, BF_EXP);
            const int e3 = (int)fmaf(s3, K_EXP, BF_EXP);
            accA += (vf2){__int_as_float(e0), __int_as_float(e1)};
            accB += (vf2){__int_as_float(e2), __int_as_float(e3)};
        }
        const vf2 accp = accA + accB;
        float ta = accp.x + accp.y;
        // Diagonal tile: this thread's j==i term contributed exactly
        // asfloat((int)BF_EXP) (s==0). Remove; off-diag tiles weight 2.
        if (diag) ta -= __int_as_float((int)BF_EXP);
        else      ta *= 2.0f;
        acc_run += ta;
    }

    // Wave-64 butterfly reduce, combine 2 waves, store block partial.
    #pragma unroll
    for (int off = 32; off > 0; off >>= 1)
        acc_run += __shfl_down(acc_run, off, 64);
    if ((tid & 63) == 0) wsum[tid >> 6] = acc_run;
    __syncthreads();
    if (tid == 0) part[blockIdx.x] = wsum[0] + wsum[1];

    cg::this_grid().sync();   // grid barrier (memory-ordering included)

    if (blockIdx.x == 0) {
        float r = 0.0f;
        for (int k = tid; k < NBLK; k += TPB)   // 4-5 coalesced loads
            r += part[k];
        #pragma unroll
        for (int off = 32; off > 0; off >>= 1)
            r += __shfl_down(r, off, 64);
        if ((tid & 63) == 0) wsum[tid >> 6] = r;
        __syncthreads();
        if (tid == 0) out[0] = wsum[0] + wsum[1];
    }
}

extern "C" void kernel_launch(void* const* d_in, const int* in_sizes, int n_in,
                              void* d_out, int out_size, void* d_ws, size_t ws_size,
                              hipStream_t stream) {
    const float2* kp = (const float2*)d_in[0];
    float* part = (float*)d_ws;   // NBLK floats, fully overwritten each call
    float* out = (float*)d_out;

    void* args[] = {(void*)&kp, (void*)&part, (void*)&out};
    hipLaunchCooperativeKernel((void*)loss_sep_coop, dim3(NBLK), dim3(TPB),
                               args, 0, stream);
}